// Round 6
// baseline (207.388 us; speedup 1.0000x reference)
//
#include <hip/hip_runtime.h>
#include <math.h>

#define BLOCK 256
#define RB 32            // rows per block -> grid = 512 = 2 blocks/CU
#define BD 64            // K-chunk
#define NE 64
#define DDIM 2048
#define TOPK 8
#define NCHUNK (DDIM / BD)   // 32

typedef float __attribute__((ext_vector_type(4))) f32x4;

__global__ __launch_bounds__(BLOCK)
__attribute__((amdgpu_waves_per_eu(2, 2)))   // pin 2 waves/SIMD -> 256-VGPR budget, no spill
void gate_kernel(
    const float* __restrict__ x,      // [NR, D]
    const float* __restrict__ w,      // [E, D]
    const float* __restrict__ bias,   // [E]
    float* __restrict__ out_w,        // [NR, K]
    float* __restrict__ out_i)        // [NR, K] indices as float
{
    __shared__ float ws[2][NE * BD];   // 2 x 16 KB, linear (global_load_lds dest)

    const int t    = threadIdx.x;
    const int lane = t & 63;
    const int wid  = t >> 6;          // wave id: owns rows wid*8 .. wid*8+7
    const int kc   = lane & 15;       // col group: cols 4kc..4kc+3 of chunk
    const int kh   = lane >> 4;       // expert group: experts kh*16 .. +15
    const int row0 = blockIdx.x * RB;

    float acc[8][16];
#pragma unroll
    for (int r = 0; r < 8; ++r)
#pragma unroll
        for (int j = 0; j < 16; ++j) acc[r][j] = 0.f;

    // ---- w staging via global_load_lds: 16KB chunk = 16 slices of 1KB ----
#define ISSUE_W(c_, wb_)                                                       \
    {                                                                          \
        const int d0_ = (c_) * BD;                                             \
        _Pragma("unroll")                                                      \
        for (int i = 0; i < 4; ++i) {                                          \
            int s  = wid * 4 + i;                                              \
            int f  = s * 256 + lane * 4;                                       \
            int wr = f >> 6, wc = f & 63;                                      \
            __builtin_amdgcn_global_load_lds(                                  \
                (const __attribute__((address_space(1))) unsigned int*)        \
                    (w + (size_t)wr * DDIM + d0_ + wc),                        \
                (__attribute__((address_space(3))) unsigned int*)((wb_) + s * 256), \
                16, 0, 0);                                                     \
        }                                                                      \
    }

    // ---- x: direct global -> regs, register-double-buffered across chunks ----
    const float* xb = x + (size_t)(row0 + wid * 8) * DDIM + kc * 4;
#define LOAD_X(dst_, c_)                                                       \
    {                                                                          \
        _Pragma("unroll")                                                      \
        for (int r = 0; r < 8; ++r)                                            \
            dst_[r] = *(const f32x4*)(xb + (size_t)r * DDIM + (c_) * BD);      \
    }

    f32x4 xA[8], xB[8];
    LOAD_X(xA, 0);
    ISSUE_W(0, ws[0]);

#define CHUNK_BODY(XCUR, XNXT, c_)                                             \
    {                                                                          \
        __syncthreads();  /* ws[c&1] DMA drained; prior buffer reads done */   \
        if ((c_) + 1 < NCHUNK) {                                               \
            ISSUE_W((c_) + 1, ws[((c_) + 1) & 1]);  /* lands by next barrier */\
            LOAD_X(XNXT, (c_) + 1);                 /* hidden under compute */ \
        }                                                                      \
        const float* wsb = ws[(c_) & 1];                                       \
        _Pragma("unroll")                                                      \
        for (int j = 0; j < 16; ++j) {                                         \
            f32x4 wj = *(const f32x4*)&wsb[(kh * 16 + j) * BD + kc * 4];       \
            _Pragma("unroll")                                                  \
            for (int r = 0; r < 8; ++r) {                                      \
                acc[r][j] += XCUR[r].x * wj.x;                                 \
                acc[r][j] += XCUR[r].y * wj.y;                                 \
                acc[r][j] += XCUR[r].z * wj.z;                                 \
                acc[r][j] += XCUR[r].w * wj.w;                                 \
            }                                                                  \
        }                                                                      \
    }

    for (int c = 0; c < NCHUNK; c += 2) {
        CHUNK_BODY(xA, xB, c);
        CHUNK_BODY(xB, xA, c + 1);
    }

    // ---- epilogue (verbatim from passing R3): fold-transpose + top-8 ----
    const float bias_l = bias[lane];

#pragma unroll
    for (int r = 0; r < 8; ++r) {
        const int gr = row0 + wid * 8 + r;

        float v[16];
#pragma unroll
        for (int j = 0; j < 16; ++j) v[j] = acc[r][j];
#pragma unroll
        for (int o = 8; o; o >>= 1) {       // fold 2o elems -> o, exchanging halves
            bool hi = (kc & o) != 0;
#pragma unroll
            for (int j = 0; j < o; ++j) {
                float send = hi ? v[j] : v[j + o];
                float keep = hi ? v[j + o] : v[j];
                v[j] = keep + __shfl_xor(send, o);
            }
        }
        float raw = v[0];                   // logit[row][expert=lane]
        float sig = 1.f / (1.f + expf(-raw));
        float vv  = raw + bias_l;

        float wsum = 0.f, myw = 0.f;
        int   myidx = 0;
#pragma unroll
        for (int k = 0; k < TOPK; ++k) {
            float m = vv;
#pragma unroll
            for (int off = 32; off; off >>= 1)
                m = fmaxf(m, __shfl_xor(m, off));
            unsigned long long b = __ballot(vv == m);
            int idx = (int)__builtin_ctzll(b);          // lowest index wins ties
            float wk = __shfl(sig, idx);
            wsum += wk;                                  // reference summation order
            if (lane == k)  { myw = wk; myidx = idx; }
            if (lane == idx) vv = -INFINITY;
        }
        if (lane < TOPK) {
            out_w[(size_t)gr * TOPK + lane] = myw / wsum;
            out_i[(size_t)gr * TOPK + lane] = (float)myidx;
        }
    }
}

extern "C" void kernel_launch(void* const* d_in, const int* in_sizes, int n_in,
                              void* d_out, int out_size, void* d_ws, size_t ws_size,
                              hipStream_t stream) {
    const float* x    = (const float*)d_in[0];
    const float* w    = (const float*)d_in[1];
    const float* bias = (const float*)d_in[2];
    const int NR = in_sizes[0] / DDIM;          // 16384 rows
    float* out   = (float*)d_out;
    float* out_w = out;
    float* out_i = out + (size_t)NR * TOPK;

    dim3 grid(NR / RB), block(BLOCK);
    hipLaunchKernelGGL(gate_kernel, grid, block, 0, stream,
                       x, w, bias, out_w, out_i);
}

// Round 7
// 130.017 us; speedup vs baseline: 1.5951x; 1.5951x over previous
//
#include <hip/hip_runtime.h>
#include <math.h>

#define BLOCK 256
#define RB 16            // rows per block -> grid = 1024 = 4 blocks/CU
#define BD 64            // K-chunk
#define NE 64
#define DDIM 2048
#define TOPK 8
#define NCHUNK (DDIM / BD)   // 32

typedef float __attribute__((ext_vector_type(4))) f32x4;

__global__ __launch_bounds__(BLOCK, 4) void gate_kernel(
    const float* __restrict__ x,      // [NR, D]
    const float* __restrict__ w,      // [E, D]
    const float* __restrict__ bias,   // [E]
    float* __restrict__ out_w,        // [NR, K]
    float* __restrict__ out_i)        // [NR, K] indices as float
{
    __shared__ float ws[2][NE * BD];       // 2 x 16 KB, linear (global_load_lds dest)
    __shared__ float logits[RB][NE + 1];   // 4.1 KB

    const int t    = threadIdx.x;
    const int lane = t & 63;
    const int wid  = t >> 6;           // 4 waves
    const int rw   = wid & 1;          // row half: rows rw*8 .. rw*8+7
    const int eh   = wid >> 1;         // expert half: experts eh*32 .. +31
    const int kc   = lane & 15;        // col group: cols 4kc..4kc+3 of chunk
    const int kh   = (lane >> 4) & 3;  // expert subgroup: 8 experts
    const int row0 = blockIdx.x * RB;

    float acc[8][8];                   // 64 VGPR: 8 rows x 8 experts
#pragma unroll
    for (int r = 0; r < 8; ++r)
#pragma unroll
        for (int j = 0; j < 8; ++j) acc[r][j] = 0.f;

    // ---- w staging via global_load_lds: 16KB chunk = 16 x 1KB slices ----
#define ISSUE_W(c_, wb_)                                                       \
    {                                                                          \
        const int d0_ = (c_) * BD;                                             \
        _Pragma("unroll")                                                      \
        for (int i = 0; i < 4; ++i) {                                          \
            int s  = wid * 4 + i;                                              \
            int f  = s * 256 + lane * 4;                                       \
            int wr = f >> 6, wc = f & 63;                                      \
            __builtin_amdgcn_global_load_lds(                                  \
                (const __attribute__((address_space(1))) unsigned int*)        \
                    (w + (size_t)wr * DDIM + d0_ + wc),                        \
                (__attribute__((address_space(3))) unsigned int*)((wb_) + s * 256), \
                16, 0, 0);                                                     \
        }                                                                      \
    }

    // ---- x: direct global -> regs, single buffer reloaded at phase end ----
    const float* xb = x + (size_t)(row0 + rw * 8) * DDIM + kc * 4;
    f32x4 xv[8];
#define LOAD_XV(c_)                                                            \
    {                                                                          \
        _Pragma("unroll")                                                      \
        for (int r = 0; r < 8; ++r)                                            \
            xv[r] = *(const f32x4*)(xb + (size_t)r * DDIM + (c_) * BD);        \
    }

    ISSUE_W(0, ws[0]);
    LOAD_XV(0);

    const int wofs = (eh * 32 + kh * 8) * BD + kc * 4;  // base LDS offset, +j*BD per expert

    for (int c = 0; c < NCHUNK; ++c) {
        __syncthreads();   // drains own DMA + xv loads; staggered across 4 blocks/CU

        if (c + 1 < NCHUNK) ISSUE_W(c + 1, ws[(c + 1) & 1]);

        const float* wsb = ws[c & 1];
#pragma unroll
        for (int j = 0; j < 8; ++j) {
            f32x4 wj = *(const f32x4*)&wsb[wofs + j * BD];
#pragma unroll
            for (int r = 0; r < 8; ++r) {
                acc[r][j] += xv[r].x * wj.x;
                acc[r][j] += xv[r].y * wj.y;
                acc[r][j] += xv[r].z * wj.z;
                acc[r][j] += xv[r].w * wj.w;
            }
        }

        // keep xv-next loads strictly after last xv use: disjoint live ranges,
        // no double-buffer pressure spike (R4 lesson)
        __builtin_amdgcn_sched_barrier(0);
        if (c + 1 < NCHUNK) LOAD_XV(c + 1);
    }

    // ---- reduce: combine kc/kc^8 partials, fold 8 values over lane bits 0-2 ----
#pragma unroll
    for (int r = 0; r < 8; ++r) {
        float v[8];
#pragma unroll
        for (int j = 0; j < 8; ++j) v[j] = acc[r][j];
#pragma unroll
        for (int j = 0; j < 8; ++j) v[j] += __shfl_xor(v[j], 8);  // kc bit3 partner
#pragma unroll
        for (int o = 4; o; o >>= 1) {      // fold 2o -> o over kc low bits
            bool hi = (kc & o) != 0;
#pragma unroll
            for (int j = 0; j < o; ++j) {
                float send = hi ? v[j] : v[j + o];
                float keep = hi ? v[j + o] : v[j];
                v[j] = keep + __shfl_xor(send, o);
            }
        }
        if (kc < 8)                        // lane (kc&7)=m holds expert eh*32+kh*8+m
            logits[rw * 8 + r][eh * 32 + kh * 8 + kc] = v[0];
    }
    __syncthreads();

    // ---- top-8 per row, wave-parallel, lane = expert (proven R0 code) ----
    const float bias_l = bias[lane];
    for (int rr = 0; rr < 4; ++rr) {
        const int r  = wid * 4 + rr;
        const int gr = row0 + r;
        float raw = logits[r][lane];
        float sig = 1.f / (1.f + expf(-raw));
        float vv  = raw + bias_l;

        float wsum = 0.f, myw = 0.f;
        int   myidx = 0;
#pragma unroll
        for (int k = 0; k < TOPK; ++k) {
            float m = vv;
#pragma unroll
            for (int off = 32; off; off >>= 1)
                m = fmaxf(m, __shfl_xor(m, off));
            unsigned long long b = __ballot(vv == m);
            int idx = (int)__builtin_ctzll(b);          // lowest index wins ties
            float wk = __shfl(sig, idx);
            wsum += wk;                                  // reference summation order
            if (lane == k)  { myw = wk; myidx = idx; }
            if (lane == idx) vv = -INFINITY;
        }
        if (lane < TOPK) {
            out_w[(size_t)gr * TOPK + lane] = myw / wsum;
            out_i[(size_t)gr * TOPK + lane] = (float)myidx;
        }
    }
}

extern "C" void kernel_launch(void* const* d_in, const int* in_sizes, int n_in,
                              void* d_out, int out_size, void* d_ws, size_t ws_size,
                              hipStream_t stream) {
    const float* x    = (const float*)d_in[0];
    const float* w    = (const float*)d_in[1];
    const float* bias = (const float*)d_in[2];
    const int NR = in_sizes[0] / DDIM;          // 16384 rows
    float* out   = (float*)d_out;
    float* out_w = out;
    float* out_i = out + (size_t)NR * TOPK;

    dim3 grid(NR / RB), block(BLOCK);
    hipLaunchKernelGGL(gate_kernel, grid, block, 0, stream,
                       x, w, bias, out_w, out_i);
}